// Round 3
// baseline (61.591 us; speedup 1.0000x reference)
//
#include <hip/hip_runtime.h>

// Dempster-Shafer Wasserstein-like distance, n=3 classes (C=4), FOCAL=1.
// Per pixel closed form:
//   h = x3/2, q = h*h/3
//   out[0]=0; out[7]=0
//   out[1]=(x0+h-1)^2+q      out[2]=(x1+h)^2+q
//   out[3]=(x0+x1+h-1)^2+q   out[4]=(x2+h)^2+q
//   out[5]=(x0+x2+h-1)^2+q   out[6]=(x1+x2+h)^2+q
//
// 2 pixels per thread: 32B load, 64B store per lane, nontemporal.
// Use clang ext_vector_type (not HIP_vector_type struct) so the
// nontemporal builtins accept the pointer type.

typedef float fvec4 __attribute__((ext_vector_type(4)));

__device__ __forceinline__ void compute_pix(const fvec4 x, fvec4& lo, fvec4& hi) {
    float h = 0.5f * x.w;
    float q = h * h * (1.0f / 3.0f);

    float b1 = x.x + h - 1.0f;
    float b2 = x.y + h;
    float b3 = x.x + x.y + h - 1.0f;
    float b4 = x.z + h;
    float b5 = x.x + x.z + h - 1.0f;
    float b6 = x.y + x.z + h;

    lo.x = 0.0f;
    lo.y = b1 * b1 + q;
    lo.z = b2 * b2 + q;
    lo.w = b3 * b3 + q;
    hi.x = b4 * b4 + q;
    hi.y = b5 * b5 + q;
    hi.z = b6 * b6 + q;
    hi.w = 0.0f;
}

__global__ __launch_bounds__(256) void wasserstein_ds_kernel(
    const fvec4* __restrict__ in,    // [npix] of (x0,x1,x2,x3)
    fvec4* __restrict__ out,         // [npix*2] (8 floats per pixel)
    int npairs)                      // npix/2
{
    int i = blockIdx.x * blockDim.x + threadIdx.x;
    if (i >= npairs) return;

    fvec4 xa = __builtin_nontemporal_load(&in[2 * i]);
    fvec4 xb = __builtin_nontemporal_load(&in[2 * i + 1]);

    fvec4 lo0, hi0, lo1, hi1;
    compute_pix(xa, lo0, hi0);
    compute_pix(xb, lo1, hi1);

    __builtin_nontemporal_store(lo0, &out[4 * i]);
    __builtin_nontemporal_store(hi0, &out[4 * i + 1]);
    __builtin_nontemporal_store(lo1, &out[4 * i + 2]);
    __builtin_nontemporal_store(hi1, &out[4 * i + 3]);
}

extern "C" void kernel_launch(void* const* d_in, const int* in_sizes, int n_in,
                              void* d_out, int out_size, void* d_ws, size_t ws_size,
                              hipStream_t stream) {
    const fvec4* in = (const fvec4*)d_in[0];
    fvec4* out = (fvec4*)d_out;
    int npix = in_sizes[0] / 4;          // B*H*W = 1,916,928
    int npairs = npix / 2;               // 958,464 (npix is even)

    int block = 256;
    int grid = (npairs + block - 1) / block;   // 3744 exact
    wasserstein_ds_kernel<<<grid, block, 0, stream>>>(in, out, npairs);
}

// Round 4
// 19.395 us; speedup vs baseline: 3.1756x; 3.1756x over previous
//
#include <hip/hip_runtime.h>

// Dempster-Shafer Wasserstein-like distance, n=3 classes (C=4), FOCAL=1.
// Per pixel closed form (h = x3/2, q = h*h/3):
//   out[0]=0                 out[4]=(x2+h)^2+q
//   out[1]=(x0+h-1)^2+q      out[5]=(x0+x2+h-1)^2+q
//   out[2]=(x1+h)^2+q        out[6]=(x1+x2+h)^2+q
//   out[3]=(x0+x1+h-1)^2+q   out[7]=0
//
// One thread per OUTPUT float4 (j = 2*pixel + half) so every store
// instruction is perfectly lane-contiguous (lane l -> base + 16*l).
// Two adjacent lanes load the same input float4 (L1 broadcast, cheap).
// NO nontemporal ops: R2 showed nt stores bypass L2 write-merging and
// doubled WRITE_SIZE (116 MB vs 61 MB ideal).

typedef float fvec4 __attribute__((ext_vector_type(4)));

__global__ __launch_bounds__(256) void wasserstein_ds_kernel(
    const fvec4* __restrict__ in,    // [npix] of (x0,x1,x2,x3)
    fvec4* __restrict__ out,         // [npix*2]
    int nout4)                       // npix*2
{
    int j = blockIdx.x * blockDim.x + threadIdx.x;
    if (j >= nout4) return;

    int p = j >> 1;
    bool hi = (j & 1) != 0;

    fvec4 x = in[p];
    float h = 0.5f * x.w;
    float q = h * h * (1.0f / 3.0f);

    // Select this half's three quadratic bases (branchless).
    float c0 = x.z + h;                                   // hi: b4
    float c1 = hi ? (x.x + x.z + h - 1.0f)                // b5
                  : (x.x + h - 1.0f);                     // b1
    float c2 = hi ? (x.y + x.z + h)                       // b6
                  : (x.y + h);                            // b2
    float c3 = x.x + x.y + h - 1.0f;                      // lo: b3

    fvec4 o;
    o.x = hi ? (c0 * c0 + q) : 0.0f;
    o.y = c1 * c1 + q;
    o.z = c2 * c2 + q;
    o.w = hi ? 0.0f : (c3 * c3 + q);

    out[j] = o;
}

extern "C" void kernel_launch(void* const* d_in, const int* in_sizes, int n_in,
                              void* d_out, int out_size, void* d_ws, size_t ws_size,
                              hipStream_t stream) {
    const fvec4* in = (const fvec4*)d_in[0];
    fvec4* out = (fvec4*)d_out;
    int npix = in_sizes[0] / 4;          // B*H*W = 1,916,928
    int nout4 = npix * 2;                // 3,833,856

    int block = 256;
    int grid = (nout4 + block - 1) / block;   // 14,976 exact
    wasserstein_ds_kernel<<<grid, block, 0, stream>>>(in, out, nout4);
}